// Round 1
// baseline (514.237 us; speedup 1.0000x reference)
//
#include <hip/hip_runtime.h>
#include <hip/hip_bf16.h>
#include <stdint.h>

typedef __attribute__((ext_vector_type(8))) short bf16x8;
typedef __attribute__((ext_vector_type(4))) float f32x4;

#define PH 130
#define NCHUNK 36

__device__ __forceinline__ short f2bf(float f) {
  uint32_t u = __builtin_bit_cast(uint32_t, f);
  u = (u + 0x7FFFu + ((u >> 16) & 1u)) >> 16;
  return (short)u;
}

__device__ __forceinline__ void gload16(const void* g, void* l) {
  __builtin_amdgcn_global_load_lds(
      (const __attribute__((address_space(1))) void*)g,
      (__attribute__((address_space(3))) void*)l, 16, 0, 0);
}

// ---------------------------------------------------------------------------
// Repack W [256co][256ci][3][3] f32 -> A [co][tap*256+ci] bf16 (tap-major K)
// ---------------------------------------------------------------------------
__global__ void wpack(const float* __restrict__ W, short* __restrict__ A) {
  int tid = blockIdx.x * 256 + threadIdx.x;
  if (tid >= 256 * 2304) return;
  int co = tid / 2304;
  int r  = tid - co * 2304;
  int tap = r >> 8, ci = r & 255;
  A[tid] = f2bf(W[((size_t)(co * 256 + ci)) * 9 + tap]);
}

// ---------------------------------------------------------------------------
// FIR upsample (separable polyphase 2x2 taps) + transpose + zero-pad:
// hT[b][p'][q'][ci] bf16, p',q' in [0,130), interior = h[p'-1][q'-1]
// block: (b*130+p', ci-tile of 64), 256 threads
// ---------------------------------------------------------------------------
__global__ void fir_up(const float* __restrict__ x, short* __restrict__ hT) {
  const int bp = blockIdx.x;
  const int b = bp / PH, pp = bp - b * PH;
  const int ci0 = blockIdx.y << 6;
  const int t = threadIdx.x;
  short* outrow = hT + ((size_t)(b * PH + pp) * PH) * 256 + ci0;

  if (pp == 0 || pp == PH - 1) {           // pad rows: zero
    for (int idx = t; idx < PH * 64; idx += 256) {
      int qp = idx >> 6, c = idx & 63;
      outrow[(size_t)qp * 256 + c] = 0;
    }
    return;
  }
  const int p = pp - 1;
  int i0, i1; float wr0, wr1;
  if (!(p & 1)) { i0 = (p >> 1) - 1; i1 = p >> 1;     wr0 = 0.25f; wr1 = 0.75f; }
  else          { i0 = p >> 1;       i1 = (p >> 1)+1; wr0 = 0.75f; wr1 = 0.25f; }

  __shared__ float X[2][64][65];           // [row][j][ci] (+1 pad)
#pragma unroll
  for (int r = 0; r < 2; ++r) {
    int ir = r ? i1 : i0;
    bool ok = (ir >= 0 && ir < 64);
#pragma unroll
    for (int it = 0; it < 4; ++it) {
      int idx = it * 256 + t;              // [0,1024): ci=idx>>4, j-quad=idx&15
      int ci = idx >> 4, jq = idx & 15;
      f32x4 v = {0.f, 0.f, 0.f, 0.f};
      if (ok)
        v = *(const f32x4*)&x[((size_t)(b * 256 + ci0 + ci) * 64 + ir) * 64 + jq * 4];
      X[r][jq * 4 + 0][ci] = v[0];
      X[r][jq * 4 + 1][ci] = v[1];
      X[r][jq * 4 + 2][ci] = v[2];
      X[r][jq * 4 + 3][ci] = v[3];
    }
  }
  __syncthreads();

  const int c = t & 63;
  for (int qp = (t >> 6); qp < PH; qp += 4) {
    float val = 0.f;
    if (qp >= 1 && qp <= 128) {
      int q = qp - 1;
      int j0, j1; float wc0, wc1;
      if (!(q & 1)) { j0 = (q >> 1) - 1; j1 = q >> 1; wc0 = 0.25f; wc1 = 0.75f; }
      else          { j0 = q >> 1;       j1 = j0 + 1; wc0 = 0.75f; wc1 = 0.25f; }
      float v00 = (j0 >= 0) ? X[0][j0][c] : 0.f;
      float v10 = (j0 >= 0) ? X[1][j0][c] : 0.f;
      float v01 = (j1 < 64) ? X[0][j1][c] : 0.f;
      float v11 = (j1 < 64) ? X[1][j1][c] : 0.f;
      val = wr0 * (wc0 * v00 + wc1 * v01) + wr1 * (wc0 * v10 + wc1 * v11);
    }
    outrow[(size_t)qp * 256 + c] = f2bf(val);
  }
}

// ---------------------------------------------------------------------------
// Implicit GEMM: y[b,co,p,q] = sum_k hT[s][k] * A[k][co] + bias[co]
// tile: 128 s (one output row, b,p fixed) x 128 co, BK=64 (one tap, 64 ci)
// 4 waves (2 s-half x 2 co-half), 4x4 frags of 16x16x32 bf16, LDS dbuf 64KB
// ---------------------------------------------------------------------------
__global__ __launch_bounds__(256) void conv3x3_gemm(
    const short* __restrict__ hT, const short* __restrict__ Wp,
    const float* __restrict__ bias, float* __restrict__ y) {
  __shared__ short lds[2][2][128 * 64];    // [buf][0=H tile,1=W tile][row128][k64]
  const int tid = threadIdx.x;
  const int lane = tid & 63, w = tid >> 6;
  const int wsq = w >> 1, wco = w & 1;
  const int ntile = blockIdx.x;            // 0..2047 : b*128 + p
  const int cotile = blockIdx.y << 7;      // 0 or 128
  const int b = ntile >> 7, p = ntile & 127;

  // staging mapping: o = issue*4096 + w*1024 + lane*16 bytes
  const int row_base = w * 8 + (lane >> 3);     // + issue*32 -> row in [0,128)
  const int koff = (lane & 7) * 8;              // k element offset in chunk

  const short* hp[4];
  const short* wp[4];
#pragma unroll
  for (int is = 0; is < 4; ++is) {
    int q = is * 32 + row_base;
    hp[is] = hT + ((size_t)(b * PH + p) * PH + q) * 256 + koff;
    int co = cotile + is * 32 + row_base;
    wp[is] = Wp + (size_t)co * 2304 + koff;
  }

  f32x4 acc[4][4];
#pragma unroll
  for (int m = 0; m < 4; ++m)
#pragma unroll
    for (int n = 0; n < 4; ++n) acc[m][n] = (f32x4){0.f, 0.f, 0.f, 0.f};

  auto stage = [&](int kc, int buf) {
    int tap = kc >> 2;
    int dm = tap / 3, dn = tap - dm * 3;
    int ci0 = (kc & 3) << 6;
    int toff = (dm * PH + dn) * 256 + ci0;   // hT elem offset for this chunk
    int woff = kc << 6;                      // A elem offset
    short* lA = &lds[buf][0][0];
    short* lB = &lds[buf][1][0];
#pragma unroll
    for (int is = 0; is < 4; ++is) {
      gload16(hp[is] + toff, lA + is * 2048 + w * 512);
      gload16(wp[is] + woff, lB + is * 2048 + w * 512);
    }
  };

  stage(0, 0);
  __syncthreads();

  for (int kc = 0; kc < NCHUNK; ++kc) {
    int cur = kc & 1;
    if (kc < NCHUNK - 1) stage(kc + 1, cur ^ 1);
    const short* LA = &lds[cur][0][0];
    const short* LB = &lds[cur][1][0];
#pragma unroll
    for (int ks = 0; ks < 2; ++ks) {
      bf16x8 af[4], bf_[4];
      int kr = ks * 32 + (lane >> 4) * 8;
#pragma unroll
      for (int m = 0; m < 4; ++m)
        af[m] = *(const bf16x8*)&LA[(wsq * 64 + m * 16 + (lane & 15)) * 64 + kr];
#pragma unroll
      for (int n = 0; n < 4; ++n)
        bf_[n] = *(const bf16x8*)&LB[(wco * 64 + n * 16 + (lane & 15)) * 64 + kr];
#pragma unroll
      for (int m = 0; m < 4; ++m)
#pragma unroll
        for (int n = 0; n < 4; ++n)
          acc[m][n] = __builtin_amdgcn_mfma_f32_16x16x32_bf16(af[m], bf_[n], acc[m][n], 0, 0, 0);
    }
    __syncthreads();
  }

  // epilogue: D row = q (regs -> consecutive q => dwordx4 stores), col = co
#pragma unroll
  for (int n = 0; n < 4; ++n) {
    int co = cotile + wco * 64 + n * 16 + (lane & 15);
    float bv = bias[co];
    float* yrow = y + (((size_t)(b * 256 + co)) * 128 + p) * 128;
#pragma unroll
    for (int m = 0; m < 4; ++m) {
      int q0 = wsq * 64 + m * 16 + ((lane >> 4) << 2);
      f32x4 v = acc[m][n];
      v[0] += bv; v[1] += bv; v[2] += bv; v[3] += bv;
      *(f32x4*)(yrow + q0) = v;
    }
  }
}

// ---------------------------------------------------------------------------
extern "C" void kernel_launch(void* const* d_in, const int* in_sizes, int n_in,
                              void* d_out, int out_size, void* d_ws, size_t ws_size,
                              hipStream_t stream) {
  const float* x    = (const float*)d_in[0];
  const float* W    = (const float*)d_in[1];
  const float* bias = (const float*)d_in[2];
  float* y = (float*)d_out;

  const size_t hT_bytes = (size_t)16 * PH * PH * 256 * 2;   // 138,444,800
  const size_t A_bytes  = (size_t)256 * 2304 * 2;           //   1,179,648
  if (ws_size < hT_bytes + A_bytes) return;                 // need ~133 MiB scratch

  short* hT = (short*)d_ws;
  short* Wp = (short*)((char*)d_ws + hT_bytes);

  wpack<<<(256 * 2304 + 255) / 256, 256, 0, stream>>>(W, Wp);
  dim3 g1(16 * PH, 4);
  fir_up<<<g1, 256, 0, stream>>>(x, hT);
  dim3 g2(2048, 2);
  conv3x3_gemm<<<g2, 256, 0, stream>>>(hT, Wp, bias, y);
}

// Round 2
// 485.729 us; speedup vs baseline: 1.0587x; 1.0587x over previous
//
#include <hip/hip_runtime.h>
#include <hip/hip_bf16.h>
#include <stdint.h>

typedef __attribute__((ext_vector_type(8))) short bf16x8;
typedef __attribute__((ext_vector_type(4))) float f32x4;

#define PH 130
#define NT 72          // K tiles: 9 taps x 256 ci / BK=32

__device__ __forceinline__ short f2bf(float f) {
  uint32_t u = __builtin_bit_cast(uint32_t, f);
  u = (u + 0x7FFFu + ((u >> 16) & 1u)) >> 16;
  return (short)u;
}

__device__ __forceinline__ void gload16(const void* g, void* l) {
  __builtin_amdgcn_global_load_lds(
      (const __attribute__((address_space(1))) void*)g,
      (__attribute__((address_space(3))) void*)l, 16, 0, 0);
}

// ---------------------------------------------------------------------------
// Repack W [256co][256ci][3][3] f32 -> A [co][tap*256+ci] bf16 (tap-major K)
// ---------------------------------------------------------------------------
__global__ void wpack(const float* __restrict__ W, short* __restrict__ A) {
  int tid = blockIdx.x * 256 + threadIdx.x;
  if (tid >= 256 * 2304) return;
  int co = tid / 2304;
  int r  = tid - co * 2304;
  int tap = r >> 8, ci = r & 255;
  A[tid] = f2bf(W[((size_t)(co * 256 + ci)) * 9 + tap]);
}

// ---------------------------------------------------------------------------
// FIR upsample (separable polyphase 2x2 taps) + transpose + zero-pad:
// hT[b][p'][q'][ci] bf16, p',q' in [0,130), interior = h[p'-1][q'-1]
// ---------------------------------------------------------------------------
__global__ void fir_up(const float* __restrict__ x, short* __restrict__ hT) {
  const int bp = blockIdx.x;
  const int b = bp / PH, pp = bp - b * PH;
  const int ci0 = blockIdx.y << 6;
  const int t = threadIdx.x;
  short* outrow = hT + ((size_t)(b * PH + pp) * PH) * 256 + ci0;

  if (pp == 0 || pp == PH - 1) {           // pad rows: zero
    for (int idx = t; idx < PH * 64; idx += 256) {
      int qp = idx >> 6, c = idx & 63;
      outrow[(size_t)qp * 256 + c] = 0;
    }
    return;
  }
  const int p = pp - 1;
  int i0, i1; float wr0, wr1;
  if (!(p & 1)) { i0 = (p >> 1) - 1; i1 = p >> 1;     wr0 = 0.25f; wr1 = 0.75f; }
  else          { i0 = p >> 1;       i1 = (p >> 1)+1; wr0 = 0.75f; wr1 = 0.25f; }

  __shared__ float X[2][64][65];           // [row][j][ci] (+1 pad)
#pragma unroll
  for (int r = 0; r < 2; ++r) {
    int ir = r ? i1 : i0;
    bool ok = (ir >= 0 && ir < 64);
#pragma unroll
    for (int it = 0; it < 4; ++it) {
      int idx = it * 256 + t;              // [0,1024): ci=idx>>4, j-quad=idx&15
      int ci = idx >> 4, jq = idx & 15;
      f32x4 v = {0.f, 0.f, 0.f, 0.f};
      if (ok)
        v = *(const f32x4*)&x[((size_t)(b * 256 + ci0 + ci) * 64 + ir) * 64 + jq * 4];
      X[r][jq * 4 + 0][ci] = v[0];
      X[r][jq * 4 + 1][ci] = v[1];
      X[r][jq * 4 + 2][ci] = v[2];
      X[r][jq * 4 + 3][ci] = v[3];
    }
  }
  __syncthreads();

  const int c = t & 63;
  for (int qp = (t >> 6); qp < PH; qp += 4) {
    float val = 0.f;
    if (qp >= 1 && qp <= 128) {
      int q = qp - 1;
      int j0, j1; float wc0, wc1;
      if (!(q & 1)) { j0 = (q >> 1) - 1; j1 = q >> 1; wc0 = 0.25f; wc1 = 0.75f; }
      else          { j0 = q >> 1;       j1 = j0 + 1; wc0 = 0.75f; wc1 = 0.25f; }
      float v00 = (j0 >= 0) ? X[0][j0][c] : 0.f;
      float v10 = (j0 >= 0) ? X[1][j0][c] : 0.f;
      float v01 = (j1 < 64) ? X[0][j1][c] : 0.f;
      float v11 = (j1 < 64) ? X[1][j1][c] : 0.f;
      val = wr0 * (wc0 * v00 + wc1 * v01) + wr1 * (wc0 * v10 + wc1 * v11);
    }
    outrow[(size_t)qp * 256 + c] = f2bf(val);
  }
}

// ---------------------------------------------------------------------------
// Implicit GEMM, m201-class schedule:
// BM=256 spatial x BN=256 co, BK=32, 8 waves (2M x 4N), ring-4 LDS dbuf,
// counted vmcnt(4)/tile, 2 fine phases/tile, T2 XOR swizzle, T5 setprio.
// LDS logical layout per tile: A[256 rows][32 k] bf16 (64B rows), B same;
// swizzle: phys = L ^ (((L>>7)&7)<<4)  (involution; rows spread 2-way = free)
// ---------------------------------------------------------------------------
__global__ __launch_bounds__(512) void conv3x3_gemm(
    const short* __restrict__ hT, const short* __restrict__ Wp,
    const float* __restrict__ bias, float* __restrict__ y) {
  __shared__ short ldsA[4][8192];          // 4 bufs x 16KB
  __shared__ short ldsB[4][8192];
  const int tid = threadIdx.x;
  const int lane = tid & 63, w = tid >> 6;
  const int wm = w >> 2, wn = w & 3;       // 2 M-waves x 4 N-waves

  const int bid = blockIdx.x;
  const int tile = (bid & 7) * 128 + (bid >> 3);   // T1 XCD swizzle (1024%8==0)
  const int b = tile >> 6, p0 = (tile & 63) * 2;   // 256 spatial rows = p0,p0+1

  // --- staging source pointers (pre-swizzled global addresses, rule 21) ---
  const short* srcA[2];
  const short* srcB[2];
#pragma unroll
  for (int i = 0; i < 2; ++i) {
    int o = i * 8192 + w * 1024 + lane * 16;       // linear LDS dest byte
    int L = o ^ (((o >> 7) & 7) << 4);             // logical byte it holds
    int row = L >> 6, slot = (L >> 4) & 3;         // logical row, 16B slot
    int p = p0 + (row >> 7), q = row & 127;
    srcA[i] = hT + ((size_t)((b * PH + p) * PH + q)) * 256 + slot * 8;
    srcB[i] = Wp + (size_t)row * 2304 + slot * 8;
  }

  auto stageA = [&](int t2) {
    int buf = t2 & 3;
    int tap = t2 >> 3, ci0 = (t2 & 7) << 5;
    int dm = tap / 3, dn = tap - dm * 3;
    int off = (dm * PH + dn) * 256 + ci0;
#pragma unroll
    for (int i = 0; i < 2; ++i)
      gload16(srcA[i] + off, &ldsA[buf][i * 4096 + w * 512]);
  };
  auto stageB = [&](int t2) {
    int buf = t2 & 3;
    int off = t2 << 5;
#pragma unroll
    for (int i = 0; i < 2; ++i)
      gload16(srcB[i] + off, &ldsB[buf][i * 4096 + w * 512]);
  };

  // logical byte bases for frag reads (+ m*1024 / + n*1024)
  const int aLbase = (wm * 128 + (lane & 15)) * 64 + (lane >> 4) * 16;
  const int bLbase = (wn * 64 + (lane & 15)) * 64 + (lane >> 4) * 16;

  f32x4 acc[8][4];
#pragma unroll
  for (int m = 0; m < 8; ++m)
#pragma unroll
    for (int n = 0; n < 4; ++n) acc[m][n] = (f32x4){0.f, 0.f, 0.f, 0.f};

  // prologue: prefetch tiles 0,1 (issue order == retire order)
  stageA(0); stageB(0);
  stageA(1); stageB(1);

  for (int t = 0; t < NT; ++t) {
    const int buf = t & 3;
    // all loads older than newest 4 (= tile t+1's) have landed => tile t ready
    if (t == NT - 1) asm volatile("s_waitcnt vmcnt(0)" ::: "memory");
    else             asm volatile("s_waitcnt vmcnt(4)" ::: "memory");
    __builtin_amdgcn_s_barrier();          // raw: no compiler vmcnt(0) drain

    const char* LA = (const char*)ldsA[buf];
    const char* LB = (const char*)ldsB[buf];

    // ---- phase 1: frag loads (A m0-3 + all B) || stage A(t+2) ----
    bf16x8 a[4], bb[4];
#pragma unroll
    for (int m = 0; m < 4; ++m) {
      int L = aLbase + m * 1024;
      int P = L ^ (((L >> 7) & 7) << 4);
      a[m] = *(const bf16x8*)(LA + P);
    }
#pragma unroll
    for (int n = 0; n < 4; ++n) {
      int L = bLbase + n * 1024;
      int P = L ^ (((L >> 7) & 7) << 4);
      bb[n] = *(const bf16x8*)(LB + P);
    }
    if (t + 2 < NT) stageA(t + 2);
    __builtin_amdgcn_s_barrier();
    asm volatile("s_waitcnt lgkmcnt(0)" ::: "memory");
    __builtin_amdgcn_sched_barrier(0);
    __builtin_amdgcn_s_setprio(1);
#pragma unroll
    for (int m = 0; m < 4; ++m)
#pragma unroll
      for (int n = 0; n < 4; ++n)
        acc[m][n] = __builtin_amdgcn_mfma_f32_16x16x32_bf16(a[m], bb[n], acc[m][n], 0, 0, 0);
    __builtin_amdgcn_s_setprio(0);
    __builtin_amdgcn_s_barrier();

    // ---- phase 2: frag loads (A m4-7, reuse bb) || stage B(t+2) ----
    bf16x8 a2[4];
#pragma unroll
    for (int m = 0; m < 4; ++m) {
      int L = aLbase + (m + 4) * 1024;
      int P = L ^ (((L >> 7) & 7) << 4);
      a2[m] = *(const bf16x8*)(LA + P);
    }
    if (t + 2 < NT) stageB(t + 2);
    __builtin_amdgcn_s_barrier();
    asm volatile("s_waitcnt lgkmcnt(0)" ::: "memory");
    __builtin_amdgcn_sched_barrier(0);
    __builtin_amdgcn_s_setprio(1);
#pragma unroll
    for (int m = 0; m < 4; ++m)
#pragma unroll
      for (int n = 0; n < 4; ++n)
        acc[m + 4][n] = __builtin_amdgcn_mfma_f32_16x16x32_bf16(a2[m], bb[n], acc[m + 4][n], 0, 0, 0);
    __builtin_amdgcn_s_setprio(0);
  }

  // ---- epilogue: D row = spatial (p0+wm, q), col = co ----
#pragma unroll
  for (int n = 0; n < 4; ++n) {
    int co = wn * 64 + n * 16 + (lane & 15);
    float bv = bias[co];
    float* yp = y + (((size_t)(b * 256 + co)) * 128 + (p0 + wm)) * 128;
#pragma unroll
    for (int m = 0; m < 8; ++m) {
      int q0 = m * 16 + ((lane >> 4) << 2);
      f32x4 v = acc[m][n];
      v[0] += bv; v[1] += bv; v[2] += bv; v[3] += bv;
      *(f32x4*)(yp + q0) = v;
    }
  }
}

// ---------------------------------------------------------------------------
extern "C" void kernel_launch(void* const* d_in, const int* in_sizes, int n_in,
                              void* d_out, int out_size, void* d_ws, size_t ws_size,
                              hipStream_t stream) {
  const float* x    = (const float*)d_in[0];
  const float* W    = (const float*)d_in[1];
  const float* bias = (const float*)d_in[2];
  float* y = (float*)d_out;

  const size_t hT_bytes = (size_t)16 * PH * PH * 256 * 2;   // 138,444,800
  const size_t A_bytes  = (size_t)256 * 2304 * 2;           //   1,179,648
  if (ws_size < hT_bytes + A_bytes) return;

  short* hT = (short*)d_ws;
  short* Wp = (short*)((char*)d_ws + hT_bytes);

  wpack<<<(256 * 2304 + 255) / 256, 256, 0, stream>>>(W, Wp);
  dim3 g1(16 * PH, 4);
  fir_up<<<g1, 256, 0, stream>>>(x, hT);
  conv3x3_gemm<<<1024, 512, 0, stream>>>(hT, Wp, bias, y);
}

// Round 3
// 471.752 us; speedup vs baseline: 1.0901x; 1.0296x over previous
//
#include <hip/hip_runtime.h>
#include <hip/hip_bf16.h>
#include <stdint.h>

typedef __attribute__((ext_vector_type(8))) short bf16x8;
typedef __attribute__((ext_vector_type(4))) float f32x4;

#define PH 130
#define ATILE_BYTES 33280   // 520 rows x 64B (4 p-rows x 130 q)
#define ABUF_SHORTS 20480   // 40960 B (5 x 8192B issues)

__device__ __forceinline__ short f2bf(float f) {
  uint32_t u = __builtin_bit_cast(uint32_t, f);
  u = (u + 0x7FFFu + ((u >> 16) & 1u)) >> 16;
  return (short)u;
}

__device__ __forceinline__ void gload16(const void* g, void* l) {
  __builtin_amdgcn_global_load_lds(
      (const __attribute__((address_space(1))) void*)g,
      (__attribute__((address_space(3))) void*)l, 16, 0, 0);
}

// ---------------------------------------------------------------------------
// Repack W [256co][256ci][3][3] f32 -> A [co][tap*256+ci] bf16 (tap-major K)
// ---------------------------------------------------------------------------
__global__ void wpack(const float* __restrict__ W, short* __restrict__ A) {
  int tid = blockIdx.x * 256 + threadIdx.x;
  if (tid >= 256 * 2304) return;
  int co = tid / 2304;
  int r  = tid - co * 2304;
  int tap = r >> 8, ci = r & 255;
  A[tid] = f2bf(W[((size_t)(co * 256 + ci)) * 9 + tap]);
}

// ---------------------------------------------------------------------------
// FIR upsample (separable polyphase 2x2 taps) + transpose + zero-pad:
// hT[b][p'][q'][ci] bf16, p',q' in [0,130), interior = h[p'-1][q'-1]
// ---------------------------------------------------------------------------
__global__ void fir_up(const float* __restrict__ x, short* __restrict__ hT) {
  const int bp = blockIdx.x;
  const int b = bp / PH, pp = bp - b * PH;
  const int ci0 = blockIdx.y << 6;
  const int t = threadIdx.x;
  short* outrow = hT + ((size_t)(b * PH + pp) * PH) * 256 + ci0;

  if (pp == 0 || pp == PH - 1) {           // pad rows: zero
    for (int idx = t; idx < PH * 64; idx += 256) {
      int qp = idx >> 6, c = idx & 63;
      outrow[(size_t)qp * 256 + c] = 0;
    }
    return;
  }
  const int p = pp - 1;
  int i0, i1; float wr0, wr1;
  if (!(p & 1)) { i0 = (p >> 1) - 1; i1 = p >> 1;     wr0 = 0.25f; wr1 = 0.75f; }
  else          { i0 = p >> 1;       i1 = (p >> 1)+1; wr0 = 0.75f; wr1 = 0.25f; }

  __shared__ float X[2][64][65];           // [row][j][ci] (+1 pad)
#pragma unroll
  for (int r = 0; r < 2; ++r) {
    int ir = r ? i1 : i0;
    bool ok = (ir >= 0 && ir < 64);
#pragma unroll
    for (int it = 0; it < 4; ++it) {
      int idx = it * 256 + t;              // [0,1024): ci=idx>>4, j-quad=idx&15
      int ci = idx >> 4, jq = idx & 15;
      f32x4 v = {0.f, 0.f, 0.f, 0.f};
      if (ok)
        v = *(const f32x4*)&x[((size_t)(b * 256 + ci0 + ci) * 64 + ir) * 64 + jq * 4];
      X[r][jq * 4 + 0][ci] = v[0];
      X[r][jq * 4 + 1][ci] = v[1];
      X[r][jq * 4 + 2][ci] = v[2];
      X[r][jq * 4 + 3][ci] = v[3];
    }
  }
  __syncthreads();

  const int c = t & 63;
  for (int qp = (t >> 6); qp < PH; qp += 4) {
    float val = 0.f;
    if (qp >= 1 && qp <= 128) {
      int q = qp - 1;
      int j0, j1; float wc0, wc1;
      if (!(q & 1)) { j0 = (q >> 1) - 1; j1 = q >> 1; wc0 = 0.25f; wc1 = 0.75f; }
      else          { j0 = q >> 1;       j1 = j0 + 1; wc0 = 0.75f; wc1 = 0.25f; }
      float v00 = (j0 >= 0) ? X[0][j0][c] : 0.f;
      float v10 = (j0 >= 0) ? X[1][j0][c] : 0.f;
      float v01 = (j1 < 64) ? X[0][j1][c] : 0.f;
      float v11 = (j1 < 64) ? X[1][j1][c] : 0.f;
      val = wr0 * (wc0 * v00 + wc1 * v01) + wr1 * (wc0 * v10 + wc1 * v11);
    }
    outrow[(size_t)qp * 256 + c] = f2bf(val);
  }
}

// ---------------------------------------------------------------------------
// Implicit GEMM with halo-staged input reuse (9 taps from one staged A-tile):
// outer c = ci-chunk (8 x 32ci), inner tap t (9). Per step: BK=32, 2 phases,
// 16 MFMA each. A halo tile [4 p][130 q][32 ci] staged ONCE per chunk (dbuf);
// B tile [256 co][32 k] ring-3, staged 2 steps ahead, counted vmcnt table.
// Swizzle (both sides): phys = L ^ (((L>>7)&7)<<4).
// ---------------------------------------------------------------------------
__global__ __launch_bounds__(512) void conv3x3_gemm(
    const short* __restrict__ hT, const short* __restrict__ Wp,
    const float* __restrict__ bias, float* __restrict__ y) {
  __shared__ short ldsA[2][ABUF_SHORTS];   // 2 x 40960 B (33280 used)
  __shared__ short ldsB[3][8192];          // 3 x 16384 B
  const int tid = threadIdx.x;
  const int lane = tid & 63, w = tid >> 6;
  const int wm = w >> 2, wn = w & 3;       // 2 M-waves x 4 N-waves

  const int bid = blockIdx.x;
  const int tile = (bid & 7) * 128 + (bid >> 3);   // T1 XCD swizzle (1024%8==0)
  const int b = tile >> 6, p0 = (tile & 63) * 2;   // 2 output rows p0,p0+1

  // --- B staging source (per lane, pre-swizzled; rule 21) ---
  const short* srcB[2];
#pragma unroll
  for (int i = 0; i < 2; ++i) {
    int o = i * 8192 + w * 1024 + lane * 16;
    int L = o ^ (((o >> 7) & 7) << 4);
    int co = L >> 6, slot = (L >> 4) & 3;
    srcB[i] = Wp + (size_t)co * 2304 + slot * 8;
  }
  // --- A staging source: 5 issues cover 33280B halo tile (tail clamped) ---
  const short* srcA[5];
#pragma unroll
  for (int i = 0; i < 5; ++i) {
    int o = i * 8192 + w * 1024 + lane * 16;
    int L = o ^ (((o >> 7) & 7) << 4);
    if (o >= ATILE_BYTES) {
      srcA[i] = hT + ((size_t)(b * PH + p0) * PH) * 256;   // clamp: harmless
    } else {
      int row = L >> 6, slot = (L >> 4) & 3;
      int pr = (row >= 390) ? 3 : (row >= 260) ? 2 : (row >= 130) ? 1 : 0;
      int q = row - pr * 130;
      srcA[i] = hT + ((size_t)((b * PH + p0 + pr) * PH + q)) * 256 + slot * 8;
    }
  }

  const int aks = (lane >> 4) * 16;        // k-slot byte within 64B row
  const int ar0 = lane & 15;               // row-in-frag
  const int brow0 = (wn * 64 + (lane & 15)) * 64 + aks;  // B frag logical base

  f32x4 acc[8][4];
#pragma unroll
  for (int m = 0; m < 8; ++m)
#pragma unroll
    for (int n = 0; n < 4; ++n) acc[m][n] = (f32x4){0.f, 0.f, 0.f, 0.f};

  // --- prologue: A(0) 5 issues, B(0), B(1) ---
#pragma unroll
  for (int i = 0; i < 5; ++i)
    gload16(srcA[i], &ldsA[0][i * 4096 + w * 512]);
#pragma unroll
  for (int i = 0; i < 2; ++i)
    gload16(srcB[i] + 0, &ldsB[0][i * 4096 + w * 512]);      // g=0: tap0,c0
#pragma unroll
  for (int i = 0; i < 2; ++i)
    gload16(srcB[i] + 256, &ldsB[1][i * 4096 + w * 512]);    // g=1: tap1,c0

  for (int c = 0; c < 8; ++c) {
    const char* LA = (const char*)&ldsA[c & 1][0];
#pragma unroll
    for (int t = 0; t < 9; ++t) {
      // ---- counted vmcnt (issue-order bookkeeping; tail-tightened) ----
      if (c == 7) {
        if (t == 8) asm volatile("s_waitcnt vmcnt(0)" ::: "memory");
        else        asm volatile("s_waitcnt vmcnt(2)" ::: "memory");
      } else if (t == 0 || t >= 7) {
        asm volatile("s_waitcnt vmcnt(2)" ::: "memory");
      } else if (t == 1 || t == 6) {
        asm volatile("s_waitcnt vmcnt(3)" ::: "memory");
      } else {
        asm volatile("s_waitcnt vmcnt(4)" ::: "memory");
      }
      __builtin_amdgcn_s_barrier();

      const int dm = t / 3, dn = t - dm * 3;               // compile-time
      const char* LB = (const char*)&ldsB[t % 3][0];
      const int aRowBase = (wm + dm) * 130 + dn + ar0;     // + m*16 per frag

      // ---- phase 1: A frags m0-3 + B frags; issue stage B(g+2) ----
      bf16x8 a[4], bb[4];
#pragma unroll
      for (int m = 0; m < 4; ++m) {
        int L = (aRowBase + m * 16) * 64 + aks;
        int P = L ^ (((L >> 7) & 7) << 4);
        a[m] = *(const bf16x8*)(LA + P);
      }
#pragma unroll
      for (int n = 0; n < 4; ++n) {
        int L = brow0 + n * 1024;
        int P = L ^ (((L >> 7) & 7) << 4);
        bb[n] = *(const bf16x8*)(LB + P);
      }
      if (!(c == 7 && t >= 7)) {
        const int tap2 = (t + 2) % 9, c2 = c + (t + 2) / 9;
        const int boff = tap2 * 256 + c2 * 32;
        short* dst = &ldsB[(t + 2) % 3][0];
#pragma unroll
        for (int i = 0; i < 2; ++i)
          gload16(srcB[i] + boff, dst + i * 4096 + w * 512);
      }
      __builtin_amdgcn_s_barrier();
      asm volatile("s_waitcnt lgkmcnt(0)" ::: "memory");
      __builtin_amdgcn_sched_barrier(0);
      __builtin_amdgcn_s_setprio(1);
#pragma unroll
      for (int m = 0; m < 4; ++m)
#pragma unroll
        for (int n = 0; n < 4; ++n)
          acc[m][n] = __builtin_amdgcn_mfma_f32_16x16x32_bf16(a[m], bb[n], acc[m][n], 0, 0, 0);
      __builtin_amdgcn_s_setprio(0);
      __builtin_amdgcn_s_barrier();

      // ---- phase 2: A frags m4-7 (reuse bb); issue 1 A-load (taps 0-4) ----
      bf16x8 a2[4];
#pragma unroll
      for (int m = 0; m < 4; ++m) {
        int L = (aRowBase + (m + 4) * 16) * 64 + aks;
        int P = L ^ (((L >> 7) & 7) << 4);
        a2[m] = *(const bf16x8*)(LA + P);
      }
      if (t < 5 && c < 7)
        gload16(srcA[t] + (c + 1) * 32, &ldsA[(c + 1) & 1][t * 4096 + w * 512]);
      __builtin_amdgcn_s_barrier();
      asm volatile("s_waitcnt lgkmcnt(0)" ::: "memory");
      __builtin_amdgcn_sched_barrier(0);
      __builtin_amdgcn_s_setprio(1);
#pragma unroll
      for (int m = 0; m < 4; ++m)
#pragma unroll
        for (int n = 0; n < 4; ++n)
          acc[m + 4][n] = __builtin_amdgcn_mfma_f32_16x16x32_bf16(a2[m], bb[n], acc[m + 4][n], 0, 0, 0);
      __builtin_amdgcn_s_setprio(0);
    }
  }

  // ---- epilogue: D row = spatial (p0+wm, q), col = co ----
#pragma unroll
  for (int n = 0; n < 4; ++n) {
    int co = wn * 64 + n * 16 + (lane & 15);
    float bv = bias[co];
    float* yp = y + (((size_t)(b * 256 + co)) * 128 + (p0 + wm)) * 128;
#pragma unroll
    for (int m = 0; m < 8; ++m) {
      int q0 = m * 16 + ((lane >> 4) << 2);
      f32x4 v = acc[m][n];
      v[0] += bv; v[1] += bv; v[2] += bv; v[3] += bv;
      *(f32x4*)(yp + q0) = v;
    }
  }
}

// ---------------------------------------------------------------------------
extern "C" void kernel_launch(void* const* d_in, const int* in_sizes, int n_in,
                              void* d_out, int out_size, void* d_ws, size_t ws_size,
                              hipStream_t stream) {
  const float* x    = (const float*)d_in[0];
  const float* W    = (const float*)d_in[1];
  const float* bias = (const float*)d_in[2];
  float* y = (float*)d_out;

  const size_t hT_bytes = (size_t)16 * PH * PH * 256 * 2;   // 138,444,800
  const size_t A_bytes  = (size_t)256 * 2304 * 2;           //   1,179,648
  if (ws_size < hT_bytes + A_bytes) return;

  short* hT = (short*)d_ws;
  short* Wp = (short*)((char*)d_ws + hT_bytes);

  wpack<<<(256 * 2304 + 255) / 256, 256, 0, stream>>>(W, Wp);
  dim3 g1(16 * PH, 4);
  fir_up<<<g1, 256, 0, stream>>>(x, hT);
  conv3x3_gemm<<<1024, 512, 0, stream>>>(hT, Wp, bias, y);
}

// Round 4
// 438.019 us; speedup vs baseline: 1.1740x; 1.0770x over previous
//
#include <hip/hip_runtime.h>
#include <hip/hip_bf16.h>
#include <stdint.h>

typedef __attribute__((ext_vector_type(8))) short bf16x8;
typedef __attribute__((ext_vector_type(4))) float f32x4;

#define PH 130
#define NT 36          // K tiles: 9 taps x 256 ci / BK=64

__device__ __forceinline__ short f2bf(float f) {
  uint32_t u = __builtin_bit_cast(uint32_t, f);
  u = (u + 0x7FFFu + ((u >> 16) & 1u)) >> 16;
  return (short)u;
}

__device__ __forceinline__ void gload16(const void* g, void* l) {
  __builtin_amdgcn_global_load_lds(
      (const __attribute__((address_space(1))) void*)g,
      (__attribute__((address_space(3))) void*)l, 16, 0, 0);
}

// ---------------------------------------------------------------------------
// Repack W [256co][256ci][3][3] f32 -> A [co][tap*256+ci] bf16 (tap-major K)
// ---------------------------------------------------------------------------
__global__ void wpack(const float* __restrict__ W, short* __restrict__ A) {
  int tid = blockIdx.x * 256 + threadIdx.x;
  if (tid >= 256 * 2304) return;
  int co = tid / 2304;
  int r  = tid - co * 2304;
  int tap = r >> 8, ci = r & 255;
  A[tid] = f2bf(W[((size_t)(co * 256 + ci)) * 9 + tap]);
}

// ---------------------------------------------------------------------------
// FIR upsample (separable polyphase 2x2 taps) + transpose + zero-pad:
// hT[b][p'][q'][ci] bf16, p',q' in [0,130), interior = h[p'-1][q'-1]
// ---------------------------------------------------------------------------
__global__ void fir_up(const float* __restrict__ x, short* __restrict__ hT) {
  const int bp = blockIdx.x;
  const int b = bp / PH, pp = bp - b * PH;
  const int ci0 = blockIdx.y << 6;
  const int t = threadIdx.x;
  short* outrow = hT + ((size_t)(b * PH + pp) * PH) * 256 + ci0;

  if (pp == 0 || pp == PH - 1) {           // pad rows: zero
    for (int idx = t; idx < PH * 64; idx += 256) {
      int qp = idx >> 6, c = idx & 63;
      outrow[(size_t)qp * 256 + c] = 0;
    }
    return;
  }
  const int p = pp - 1;
  int i0, i1; float wr0, wr1;
  if (!(p & 1)) { i0 = (p >> 1) - 1; i1 = p >> 1;     wr0 = 0.25f; wr1 = 0.75f; }
  else          { i0 = p >> 1;       i1 = (p >> 1)+1; wr0 = 0.75f; wr1 = 0.25f; }

  __shared__ float X[2][64][65];           // [row][j][ci] (+1 pad)
#pragma unroll
  for (int r = 0; r < 2; ++r) {
    int ir = r ? i1 : i0;
    bool ok = (ir >= 0 && ir < 64);
#pragma unroll
    for (int it = 0; it < 4; ++it) {
      int idx = it * 256 + t;              // [0,1024): ci=idx>>4, j-quad=idx&15
      int ci = idx >> 4, jq = idx & 15;
      f32x4 v = {0.f, 0.f, 0.f, 0.f};
      if (ok)
        v = *(const f32x4*)&x[((size_t)(b * 256 + ci0 + ci) * 64 + ir) * 64 + jq * 4];
      X[r][jq * 4 + 0][ci] = v[0];
      X[r][jq * 4 + 1][ci] = v[1];
      X[r][jq * 4 + 2][ci] = v[2];
      X[r][jq * 4 + 3][ci] = v[3];
    }
  }
  __syncthreads();

  const int c = t & 63;
  for (int qp = (t >> 6); qp < PH; qp += 4) {
    float val = 0.f;
    if (qp >= 1 && qp <= 128) {
      int q = qp - 1;
      int j0, j1; float wc0, wc1;
      if (!(q & 1)) { j0 = (q >> 1) - 1; j1 = q >> 1; wc0 = 0.25f; wc1 = 0.75f; }
      else          { j0 = q >> 1;       j1 = j0 + 1; wc0 = 0.75f; wc1 = 0.25f; }
      float v00 = (j0 >= 0) ? X[0][j0][c] : 0.f;
      float v10 = (j0 >= 0) ? X[1][j0][c] : 0.f;
      float v01 = (j1 < 64) ? X[0][j1][c] : 0.f;
      float v11 = (j1 < 64) ? X[1][j1][c] : 0.f;
      val = wr0 * (wc0 * v00 + wc1 * v01) + wr1 * (wc0 * v10 + wc1 * v11);
    }
    outrow[(size_t)qp * 256 + c] = f2bf(val);
  }
}

// ---------------------------------------------------------------------------
// Implicit GEMM, m201-faithful 4-phase schedule:
// BM=256 spatial x BN=256 co, BK=64 (NT=36 K-tiles), 8 waves (2M x 4N).
// Per iter: 4 phases x 16 MFMA; ONE vmcnt(6) per iter (P4-close) gating the
// NEXT tile; dead-slot dbuf: A(t+1)hi staged @P1, B(t+2)lo @P3,
// B(t+2)hi+A(t+2)lo @P4. Swizzle phys = L ^ (((L>>7)&7)<<4), precomputed
// per-lane bases (row&7 invariant under m*16) -> frag reads are base+imm.
// ---------------------------------------------------------------------------
__global__ __launch_bounds__(512) void conv3x3_gemm(
    const short* __restrict__ hT, const short* __restrict__ Wp,
    const float* __restrict__ bias, float* __restrict__ y) {
  __shared__ short ldsA[2][16384];         // 2 x 32KB tiles [256 rows][64 k]
  __shared__ short ldsB[2][16384];
  const int tid = threadIdx.x;
  const int lane = tid & 63, w = tid >> 6;
  const int wm = w >> 2, wn = w & 3;       // 2 M-waves x 4 N-waves

  const int bid = blockIdx.x;
  const int tile = (bid & 7) * 128 + (bid >> 3);   // T1 XCD swizzle (1024%8==0)
  const int b = tile >> 6, p0 = (tile & 63) * 2;   // 2 output rows p0,p0+1

  // --- staging sources: idx = h*2+i, dest o = h*16384 + i*8192 + w*1024 + lane*16
  const short* srcA[4];
  const short* srcB[4];
#pragma unroll
  for (int h = 0; h < 2; ++h)
#pragma unroll
    for (int i = 0; i < 2; ++i) {
      int o = h * 16384 + i * 8192 + w * 1024 + lane * 16;
      int L = o ^ (((o >> 7) & 7) << 4);
      int row = L >> 7, kk = (L & 127) >> 1;
      int pr = row >> 7, q = row & 127;
      srcA[h * 2 + i] = hT + ((size_t)((b * PH + p0 + pr) * PH + q)) * 256 + kk;
      srcB[h * 2 + i] = Wp + (size_t)row * 2304 + kk;
    }

  auto offA = [&](int t) {
    int tap = t >> 2, ci0 = (t & 3) << 6;
    int dm = tap / 3, dn = tap - dm * 3;
    return (dm * PH + dn) * 256 + ci0;
  };
  auto offB = [&](int t) { return (t >> 2) * 256 + ((t & 3) << 6); };

  auto stageA = [&](int t, int h) {        // one half (2 gloads)
    int o = offA(t);
    short* dst = &ldsA[t & 1][h * 8192];
#pragma unroll
    for (int i = 0; i < 2; ++i)
      gload16(srcA[h * 2 + i] + o, dst + i * 4096 + w * 512);
  };
  auto stageB = [&](int t, int h) {
    int o = offB(t);
    short* dst = &ldsB[t & 1][h * 8192];
#pragma unroll
    for (int i = 0; i < 2; ++i)
      gload16(srcB[h * 2 + i] + o, dst + i * 4096 + w * 512);
  };

  // --- precomputed swizzled frag bases (bytes); reads = base + m*2048 (+imm)
  int aP[2], bP[2];
#pragma unroll
  for (int ks = 0; ks < 2; ++ks) {
    int La = (wm * 128 + (lane & 15)) * 128 + (lane >> 4) * 16 + ks * 64;
    aP[ks] = La ^ ((lane & 7) << 4);
    int Lb = (wn * 64 + (lane & 15)) * 128 + (lane >> 4) * 16 + ks * 64;
    bP[ks] = Lb ^ ((lane & 7) << 4);
  }

  f32x4 acc[8][4];
#pragma unroll
  for (int m = 0; m < 8; ++m)
#pragma unroll
    for (int n = 0; n < 4; ++n) acc[m][n] = (f32x4){0.f, 0.f, 0.f, 0.f};

  // --- prologue: B0lo,B0hi,A0lo,A0hi,B1lo,B1hi,A1lo  (7 halves, order matters)
  stageB(0, 0); stageB(0, 1); stageA(0, 0); stageA(0, 1);
  stageB(1, 0); stageB(1, 1); stageA(1, 0);
  asm volatile("s_waitcnt vmcnt(6)" ::: "memory");   // gate tile 0
  __builtin_amdgcn_s_barrier();

  for (int t = 0; t < NT; ++t) {
    const char* LA = (const char*)&ldsA[t & 1][0];
    const char* LB = (const char*)&ldsB[t & 1][0];

    // ================= P1: A m0-3 (both ks) + B ks0 ; stage A(t+1)hi ======
    bf16x8 a0[4], a1[4], b0[4], b1[4];
#pragma unroll
    for (int m = 0; m < 4; ++m) {
      a0[m] = *(const bf16x8*)(LA + aP[0] + m * 2048);
      a1[m] = *(const bf16x8*)(LA + aP[1] + m * 2048);
    }
#pragma unroll
    for (int n = 0; n < 4; ++n)
      b0[n] = *(const bf16x8*)(LB + bP[0] + n * 2048);
    if (t + 1 < NT) stageA(t + 1, 1);
    __builtin_amdgcn_s_barrier();
    asm volatile("s_waitcnt lgkmcnt(0)" ::: "memory");
    __builtin_amdgcn_sched_barrier(0);
    __builtin_amdgcn_s_setprio(1);
#pragma unroll
    for (int m = 0; m < 4; ++m)
#pragma unroll
      for (int n = 0; n < 4; ++n)
        acc[m][n] = __builtin_amdgcn_mfma_f32_16x16x32_bf16(a0[m], b0[n], acc[m][n], 0, 0, 0);
    __builtin_amdgcn_s_setprio(0);
    __builtin_amdgcn_s_barrier();

    // ================= P2: B ks1 ; no stage ==============================
#pragma unroll
    for (int n = 0; n < 4; ++n)
      b1[n] = *(const bf16x8*)(LB + bP[1] + n * 2048);
    __builtin_amdgcn_s_barrier();
    asm volatile("s_waitcnt lgkmcnt(0)" ::: "memory");
    __builtin_amdgcn_sched_barrier(0);
    __builtin_amdgcn_s_setprio(1);
#pragma unroll
    for (int m = 0; m < 4; ++m)
#pragma unroll
      for (int n = 0; n < 4; ++n)
        acc[m][n] = __builtin_amdgcn_mfma_f32_16x16x32_bf16(a1[m], b1[n], acc[m][n], 0, 0, 0);
    __builtin_amdgcn_s_setprio(0);
    __builtin_amdgcn_s_barrier();

    // ================= P3: A m4-7 (both ks) ; stage B(t+2)lo =============
    bf16x8 c0[4], c1[4];
#pragma unroll
    for (int m = 0; m < 4; ++m) {
      c0[m] = *(const bf16x8*)(LA + aP[0] + (m + 4) * 2048);
      c1[m] = *(const bf16x8*)(LA + aP[1] + (m + 4) * 2048);
    }
    if (t + 2 < NT) stageB(t + 2, 0);
    __builtin_amdgcn_s_barrier();
    asm volatile("s_waitcnt lgkmcnt(0)" ::: "memory");
    __builtin_amdgcn_sched_barrier(0);
    __builtin_amdgcn_s_setprio(1);
#pragma unroll
    for (int m = 0; m < 4; ++m)
#pragma unroll
      for (int n = 0; n < 4; ++n)
        acc[m + 4][n] = __builtin_amdgcn_mfma_f32_16x16x32_bf16(c0[m], b0[n], acc[m + 4][n], 0, 0, 0);
    __builtin_amdgcn_s_setprio(0);
    __builtin_amdgcn_s_barrier();

    // ================= P4: stage B(t+2)hi + A(t+2)lo ; vmcnt gate t+1 ====
    if (t + 2 < NT) { stageB(t + 2, 1); stageA(t + 2, 0); }
    __builtin_amdgcn_sched_barrier(0);
    __builtin_amdgcn_s_setprio(1);
#pragma unroll
    for (int m = 0; m < 4; ++m)
#pragma unroll
      for (int n = 0; n < 4; ++n)
        acc[m + 4][n] = __builtin_amdgcn_mfma_f32_16x16x32_bf16(c1[m], b1[n], acc[m + 4][n], 0, 0, 0);
    __builtin_amdgcn_s_setprio(0);
    if (t == NT - 2)      asm volatile("s_waitcnt vmcnt(0)" ::: "memory");
    else if (t < NT - 2)  asm volatile("s_waitcnt vmcnt(6)" ::: "memory");
    __builtin_amdgcn_s_barrier();
  }

  // ---- epilogue: D row = spatial (p0+wm, q), col = co ----
#pragma unroll
  for (int n = 0; n < 4; ++n) {
    int co = wn * 64 + n * 16 + (lane & 15);
    float bv = bias[co];
    float* yp = y + (((size_t)(b * 256 + co)) * 128 + (p0 + wm)) * 128;
#pragma unroll
    for (int m = 0; m < 8; ++m) {
      int q0 = m * 16 + ((lane >> 4) << 2);
      f32x4 v = acc[m][n];
      v[0] += bv; v[1] += bv; v[2] += bv; v[3] += bv;
      *(f32x4*)(yp + q0) = v;
    }
  }
}

// ---------------------------------------------------------------------------
extern "C" void kernel_launch(void* const* d_in, const int* in_sizes, int n_in,
                              void* d_out, int out_size, void* d_ws, size_t ws_size,
                              hipStream_t stream) {
  const float* x    = (const float*)d_in[0];
  const float* W    = (const float*)d_in[1];
  const float* bias = (const float*)d_in[2];
  float* y = (float*)d_out;

  const size_t hT_bytes = (size_t)16 * PH * PH * 256 * 2;   // 138,444,800
  const size_t A_bytes  = (size_t)256 * 2304 * 2;           //   1,179,648
  if (ws_size < hT_bytes + A_bytes) return;

  short* hT = (short*)d_ws;
  short* Wp = (short*)((char*)d_ws + hT_bytes);

  wpack<<<(256 * 2304 + 255) / 256, 256, 0, stream>>>(W, Wp);
  dim3 g1(16 * PH, 4);
  fir_up<<<g1, 256, 0, stream>>>(x, hT);
  conv3x3_gemm<<<1024, 512, 0, stream>>>(hT, Wp, bias, y);
}

// Round 5
// 429.533 us; speedup vs baseline: 1.1972x; 1.0198x over previous
//
#include <hip/hip_runtime.h>
#include <hip/hip_bf16.h>
#include <stdint.h>

typedef __attribute__((ext_vector_type(8))) short bf16x8;
typedef __attribute__((ext_vector_type(4))) float f32x4;

#define PH 130
#define NT 36          // K tiles: 9 taps x 256 ci / BK=64

__device__ __forceinline__ short f2bf(float f) {
  uint32_t u = __builtin_bit_cast(uint32_t, f);
  u = (u + 0x7FFFu + ((u >> 16) & 1u)) >> 16;
  return (short)u;
}

__device__ __forceinline__ void gload16(const void* g, void* l) {
  __builtin_amdgcn_global_load_lds(
      (const __attribute__((address_space(1))) void*)g,
      (__attribute__((address_space(3))) void*)l, 16, 0, 0);
}

// ---------------------------------------------------------------------------
// Repack W [256co][256ci][3][3] f32 -> A [co][tap*256+ci] bf16 (tap-major K)
// ---------------------------------------------------------------------------
__global__ void wpack(const float* __restrict__ W, short* __restrict__ A) {
  int tid = blockIdx.x * 256 + threadIdx.x;
  if (tid >= 256 * 2304) return;
  int co = tid / 2304;
  int r  = tid - co * 2304;
  int tap = r >> 8, ci = r & 255;
  A[tid] = f2bf(W[((size_t)(co * 256 + ci)) * 9 + tap]);
}

// ---------------------------------------------------------------------------
// FIR upsample (separable polyphase 2x2 taps) + transpose + zero-pad:
// hT[b][p'][q'][ci] bf16, p',q' in [0,130), interior = h[p'-1][q'-1]
// ---------------------------------------------------------------------------
__global__ void fir_up(const float* __restrict__ x, short* __restrict__ hT) {
  const int bp = blockIdx.x;
  const int b = bp / PH, pp = bp - b * PH;
  const int ci0 = blockIdx.y << 6;
  const int t = threadIdx.x;
  short* outrow = hT + ((size_t)(b * PH + pp) * PH) * 256 + ci0;

  if (pp == 0 || pp == PH - 1) {           // pad rows: zero
    for (int idx = t; idx < PH * 64; idx += 256) {
      int qp = idx >> 6, c = idx & 63;
      outrow[(size_t)qp * 256 + c] = 0;
    }
    return;
  }
  const int p = pp - 1;
  int i0, i1; float wr0, wr1;
  if (!(p & 1)) { i0 = (p >> 1) - 1; i1 = p >> 1;     wr0 = 0.25f; wr1 = 0.75f; }
  else          { i0 = p >> 1;       i1 = (p >> 1)+1; wr0 = 0.75f; wr1 = 0.25f; }

  __shared__ float X[2][64][65];           // [row][j][ci] (+1 pad)
#pragma unroll
  for (int r = 0; r < 2; ++r) {
    int ir = r ? i1 : i0;
    bool ok = (ir >= 0 && ir < 64);
#pragma unroll
    for (int it = 0; it < 4; ++it) {
      int idx = it * 256 + t;              // [0,1024): ci=idx>>4, j-quad=idx&15
      int ci = idx >> 4, jq = idx & 15;
      f32x4 v = {0.f, 0.f, 0.f, 0.f};
      if (ok)
        v = *(const f32x4*)&x[((size_t)(b * 256 + ci0 + ci) * 64 + ir) * 64 + jq * 4];
      X[r][jq * 4 + 0][ci] = v[0];
      X[r][jq * 4 + 1][ci] = v[1];
      X[r][jq * 4 + 2][ci] = v[2];
      X[r][jq * 4 + 3][ci] = v[3];
    }
  }
  __syncthreads();

  const int c = t & 63;
  for (int qp = (t >> 6); qp < PH; qp += 4) {
    float val = 0.f;
    if (qp >= 1 && qp <= 128) {
      int q = qp - 1;
      int j0, j1; float wc0, wc1;
      if (!(q & 1)) { j0 = (q >> 1) - 1; j1 = q >> 1; wc0 = 0.25f; wc1 = 0.75f; }
      else          { j0 = q >> 1;       j1 = j0 + 1; wc0 = 0.75f; wc1 = 0.25f; }
      float v00 = (j0 >= 0) ? X[0][j0][c] : 0.f;
      float v10 = (j0 >= 0) ? X[1][j0][c] : 0.f;
      float v01 = (j1 < 64) ? X[0][j1][c] : 0.f;
      float v11 = (j1 < 64) ? X[1][j1][c] : 0.f;
      val = wr0 * (wc0 * v00 + wc1 * v01) + wr1 * (wc0 * v10 + wc1 * v11);
    }
    outrow[(size_t)qp * 256 + c] = f2bf(val);
  }
}

// ---------------------------------------------------------------------------
// Implicit GEMM, 2-phase/K-tile, 32 MFMA per barrier-pair:
// BM=256 spatial x BN=256 co, BK=64 (NT=36), 8 waves (2M x 4N), dbuf LDS.
// P1: read A m0-3 + all B (16 b128), stage A(t+1) full tile -> 32 MFMA.
// P2: read A m4-7 (8 b128), stage B(t+2) full tile -> 32 MFMA; ONE vmcnt(4)
// at P2-close gates tile t+1 (forces B(t+1)+A(t+1), leaves B(t+2) in flight).
// Swizzle phys = L ^ (((L>>7)&7)<<4); per-lane bases precomputed (row&7
// invariant under m*16) so every frag read is base + immediate.
// ---------------------------------------------------------------------------
__global__ __launch_bounds__(512) void conv3x3_gemm(
    const short* __restrict__ hT, const short* __restrict__ Wp,
    const float* __restrict__ bias, float* __restrict__ y) {
  __shared__ short ldsA[2][16384];         // 2 x 32KB tiles [256 rows][64 k]
  __shared__ short ldsB[2][16384];
  const int tid = threadIdx.x;
  const int lane = tid & 63, w = tid >> 6;
  const int wm = w >> 2, wn = w & 3;       // 2 M-waves x 4 N-waves

  const int bid = blockIdx.x;
  const int tile = (bid & 7) * 128 + (bid >> 3);   // T1 XCD swizzle (1024%8==0)
  const int b = tile >> 6, p0 = (tile & 63) * 2;   // 2 output rows p0,p0+1

  // --- staging sources: idx = h*2+i, dest o = h*16384 + i*8192 + w*1024 + lane*16
  const short* srcA[4];
  const short* srcB[4];
#pragma unroll
  for (int h = 0; h < 2; ++h)
#pragma unroll
    for (int i = 0; i < 2; ++i) {
      int o = h * 16384 + i * 8192 + w * 1024 + lane * 16;
      int L = o ^ (((o >> 7) & 7) << 4);
      int row = L >> 7, kk = (L & 127) >> 1;
      int pr = row >> 7, q = row & 127;
      srcA[h * 2 + i] = hT + ((size_t)((b * PH + p0 + pr) * PH + q)) * 256 + kk;
      srcB[h * 2 + i] = Wp + (size_t)row * 2304 + kk;
    }

  auto offA = [&](int t) {
    int tap = t >> 2, ci0 = (t & 3) << 6;
    int dm = (tap >= 6) ? 2 : (tap >= 3) ? 1 : 0;  // tap/3 without div
    int dn = tap - 3 * dm;
    return (dm * PH + dn) * 256 + ci0;
  };
  auto offB = [&](int t) { return (t >> 2) * 256 + ((t & 3) << 6); };

  auto stageA = [&](int t) {               // full tile: 4 gloads
    int o = offA(t);
    short* dst = &ldsA[t & 1][0];
#pragma unroll
    for (int j = 0; j < 4; ++j)
      gload16(srcA[j] + o, dst + (j >> 1) * 8192 + (j & 1) * 4096 + w * 512);
  };
  auto stageB = [&](int t) {
    int o = offB(t);
    short* dst = &ldsB[t & 1][0];
#pragma unroll
    for (int j = 0; j < 4; ++j)
      gload16(srcB[j] + o, dst + (j >> 1) * 8192 + (j & 1) * 4096 + w * 512);
  };

  // --- precomputed swizzled frag bases (bytes); reads = base + m*2048
  int aP[2], bP[2];
#pragma unroll
  for (int ks = 0; ks < 2; ++ks) {
    int La = (wm * 128 + (lane & 15)) * 128 + (lane >> 4) * 16 + ks * 64;
    aP[ks] = La ^ ((lane & 7) << 4);
    int Lb = (wn * 64 + (lane & 15)) * 128 + (lane >> 4) * 16 + ks * 64;
    bP[ks] = Lb ^ ((lane & 7) << 4);
  }

  f32x4 acc[8][4];
#pragma unroll
  for (int m = 0; m < 8; ++m)
#pragma unroll
    for (int n = 0; n < 4; ++n) acc[m][n] = (f32x4){0.f, 0.f, 0.f, 0.f};

  // --- prologue: B(0), A(0), B(1) = 12 gloads; vmcnt(4) forces B0+A0 ---
  stageB(0); stageA(0); stageB(1);
  asm volatile("s_waitcnt vmcnt(4)" ::: "memory");
  __builtin_amdgcn_s_barrier();

  for (int t = 0; t < NT; ++t) {
    const char* LA = (const char*)&ldsA[t & 1][0];
    const char* LB = (const char*)&ldsB[t & 1][0];

    // ===== P1: A m0-3 (8 b128) + B all (8 b128); stage A(t+1); 32 MFMA ====
    bf16x8 a0[4], a1[4], b0[4], b1[4];
#pragma unroll
    for (int m = 0; m < 4; ++m) {
      a0[m] = *(const bf16x8*)(LA + aP[0] + m * 2048);
      a1[m] = *(const bf16x8*)(LA + aP[1] + m * 2048);
    }
#pragma unroll
    for (int n = 0; n < 4; ++n) {
      b0[n] = *(const bf16x8*)(LB + bP[0] + n * 2048);
      b1[n] = *(const bf16x8*)(LB + bP[1] + n * 2048);
    }
    if (t + 1 < NT) stageA(t + 1);
    __builtin_amdgcn_s_barrier();
    asm volatile("s_waitcnt lgkmcnt(0)" ::: "memory");
    __builtin_amdgcn_sched_barrier(0);
    __builtin_amdgcn_s_setprio(1);
#pragma unroll
    for (int m = 0; m < 4; ++m)
#pragma unroll
      for (int n = 0; n < 4; ++n) {
        acc[m][n] = __builtin_amdgcn_mfma_f32_16x16x32_bf16(a0[m], b0[n], acc[m][n], 0, 0, 0);
        acc[m][n] = __builtin_amdgcn_mfma_f32_16x16x32_bf16(a1[m], b1[n], acc[m][n], 0, 0, 0);
      }
    __builtin_amdgcn_s_setprio(0);
    __builtin_amdgcn_s_barrier();

    // ===== P2: A m4-7 (8 b128); stage B(t+2); 32 MFMA; vmcnt gate =========
    bf16x8 c0[4], c1[4];
#pragma unroll
    for (int m = 0; m < 4; ++m) {
      c0[m] = *(const bf16x8*)(LA + aP[0] + (m + 4) * 2048);
      c1[m] = *(const bf16x8*)(LA + aP[1] + (m + 4) * 2048);
    }
    if (t + 2 < NT) stageB(t + 2);
    __builtin_amdgcn_s_barrier();
    asm volatile("s_waitcnt lgkmcnt(0)" ::: "memory");
    __builtin_amdgcn_sched_barrier(0);
    __builtin_amdgcn_s_setprio(1);
#pragma unroll
    for (int m = 0; m < 4; ++m)
#pragma unroll
      for (int n = 0; n < 4; ++n) {
        acc[m + 4][n] = __builtin_amdgcn_mfma_f32_16x16x32_bf16(c0[m], b0[n], acc[m + 4][n], 0, 0, 0);
        acc[m + 4][n] = __builtin_amdgcn_mfma_f32_16x16x32_bf16(c1[m], b1[n], acc[m + 4][n], 0, 0, 0);
      }
    __builtin_amdgcn_s_setprio(0);
    if (t == NT - 2)      asm volatile("s_waitcnt vmcnt(0)" ::: "memory");
    else if (t < NT - 2)  asm volatile("s_waitcnt vmcnt(4)" ::: "memory");
    if (t < NT - 1) __builtin_amdgcn_s_barrier();
  }

  // ---- epilogue: D row = spatial (p0+wm, q), col = co ----
#pragma unroll
  for (int n = 0; n < 4; ++n) {
    int co = wn * 64 + n * 16 + (lane & 15);
    float bv = bias[co];
    float* yp = y + (((size_t)(b * 256 + co)) * 128 + (p0 + wm)) * 128;
#pragma unroll
    for (int m = 0; m < 8; ++m) {
      int q0 = m * 16 + ((lane >> 4) << 2);
      f32x4 v = acc[m][n];
      v[0] += bv; v[1] += bv; v[2] += bv; v[3] += bv;
      *(f32x4*)(yp + q0) = v;
    }
  }
}

// ---------------------------------------------------------------------------
extern "C" void kernel_launch(void* const* d_in, const int* in_sizes, int n_in,
                              void* d_out, int out_size, void* d_ws, size_t ws_size,
                              hipStream_t stream) {
  const float* x    = (const float*)d_in[0];
  const float* W    = (const float*)d_in[1];
  const float* bias = (const float*)d_in[2];
  float* y = (float*)d_out;

  const size_t hT_bytes = (size_t)16 * PH * PH * 256 * 2;   // 138,444,800
  const size_t A_bytes  = (size_t)256 * 2304 * 2;           //   1,179,648
  if (ws_size < hT_bytes + A_bytes) return;

  short* hT = (short*)d_ws;
  short* Wp = (short*)((char*)d_ws + hT_bytes);

  wpack<<<(256 * 2304 + 255) / 256, 256, 0, stream>>>(W, Wp);
  dim3 g1(16 * PH, 4);
  fir_up<<<g1, 256, 0, stream>>>(x, hT);
  conv3x3_gemm<<<1024, 512, 0, stream>>>(hT, Wp, bias, y);
}